// Round 4
// baseline (440.684 us; speedup 1.0000x reference)
//
#include <hip/hip_runtime.h>
#include <math.h>

typedef short s16x8 __attribute__((ext_vector_type(8)));
typedef float f32x4 __attribute__((ext_vector_type(4)));
typedef unsigned short u16;
typedef unsigned short u16x4 __attribute__((ext_vector_type(4)));
typedef unsigned short u16x8 __attribute__((ext_vector_type(8)));

constexpr int cB    = 16;
constexpr int cLQ   = 1024;
constexpr int cD    = 256;
constexpr int cH    = 8;
constexpr int cLVTOT= 5440;
constexpr int cNTOK = cB * cLQ;    // 16384
constexpr int cNV   = cB * cLVTOT; // 87040

__device__ __forceinline__ u16 f2b(float f) {
    __bf16 h = (__bf16)f;
    u16 u;
    __builtin_memcpy(&u, &h, 2);
    return u;
}
__device__ __forceinline__ float bl(unsigned x) {
    return __uint_as_float(x << 16);
}
__device__ __forceinline__ u16x8 cvt8(float4 a, float4 b) {
    return (u16x8){ f2b(a.x), f2b(a.y), f2b(a.z), f2b(a.w),
                    f2b(b.x), f2b(b.y), f2b(b.z), f2b(b.w) };
}

// ===== single fused conversion pass: tgt/qb + src + all 8 weight tensors + bias concat =====
// 16 f32 per thread (4 independent float4 loads -> 2 full-width 16B stores): 4x the
// memory-level parallelism and 2x the store width of the old 1-float4/thread version.
// Block segments: [0,1024) tgt/qb | [1024,6464) src | [6464,6712) weights | 6712 bias.
struct WArgs { const float4* src[8]; };
__global__ __launch_bounds__(256) void prep_all(const float4* __restrict__ t,
                                                const float4* __restrict__ q,
                                                u16x8* __restrict__ tb,
                                                u16x8* __restrict__ qb,
                                                const float4* __restrict__ src,
                                                u16x8* __restrict__ srcb,
                                                WArgs wa,
                                                u16x8* __restrict__ wout,
                                                const float* __restrict__ off_b,
                                                const float* __restrict__ attw_b,
                                                float* __restrict__ biasoa) {
    int bid = blockIdx.x;
    if (bid < 1024) {
        size_t u = (size_t)bid * 256 + threadIdx.x;   // 16-f32 unit over 16384x256 tgt
        const float4* tp = t + u * 4;
        const float4* qp = q + u * 4;
        float4 a0 = tp[0], a1 = tp[1], a2 = tp[2], a3 = tp[3];
        float4 b0 = qp[0], b1 = qp[1], b2 = qp[2], b3 = qp[3];
        tb[u * 2]     = cvt8(a0, a1);
        tb[u * 2 + 1] = cvt8(a2, a3);
        float4 s0 = {a0.x + b0.x, a0.y + b0.y, a0.z + b0.z, a0.w + b0.w};
        float4 s1 = {a1.x + b1.x, a1.y + b1.y, a1.z + b1.z, a1.w + b1.w};
        float4 s2 = {a2.x + b2.x, a2.y + b2.y, a2.z + b2.z, a2.w + b2.w};
        float4 s3 = {a3.x + b3.x, a3.y + b3.y, a3.z + b3.z, a3.w + b3.w};
        qb[u * 2]     = cvt8(s0, s1);
        qb[u * 2 + 1] = cvt8(s2, s3);
    } else if (bid < 6464) {
        size_t u = (size_t)(bid - 1024) * 256 + threadIdx.x;   // over 87040x256 src
        const float4* sp = src + u * 4;
        float4 a0 = sp[0], a1 = sp[1], a2 = sp[2], a3 = sp[3];
        srcb[u * 2]     = cvt8(a0, a1);
        srcb[u * 2 + 1] = cvt8(a2, a3);
    } else if (bid < 6712) {
        int u = (bid - 6464) * 256 + threadIdx.x;   // 16-f32 unit over concat'd weights
        int i = u * 4;                               // float4 index; all tensor boundaries %4==0
        int s, off;
        if (i < 98304) {
            if (i < 65536) { if (i < 49152) { s = 0; off = i; } else { s = 1; off = i - 49152; } }
            else           { if (i < 81920) { s = 2; off = i - 65536; } else { s = 3; off = i - 81920; } }
        } else {
            if (i < 122880){ if (i < 106496){ s = 4; off = i - 98304; } else { s = 5; off = i - 106496; } }
            else           { if (i < 188416){ s = 6; off = i - 122880; } else { s = 7; off = i - 188416; } }
        }
        const float4* wp = wa.src[s] + off;
        float4 a0 = wp[0], a1 = wp[1], a2 = wp[2], a3 = wp[3];
        wout[(size_t)u * 2]     = cvt8(a0, a1);
        wout[(size_t)u * 2 + 1] = cvt8(a2, a3);
    } else {
        int tix = threadIdx.x;
        biasoa[tix] = off_b[tix];
        if (tix < 128) biasoa[256 + tix] = attw_b[tix];
    }
}

// ===== fused QKV projection + value projection (one grid, identical 128x128xK256 blocks) =====
// bid < 1360: value projection (srcb @ value_w -> valb).  bid >= 1360: QKV (qb/tgtb @ in_proj).
__global__ __launch_bounds__(256) void gemm_qkv_val(const u16* __restrict__ A0,
                                                    const u16* __restrict__ A1,
                                                    const u16* __restrict__ Wt,
                                                    const float* __restrict__ bias,
                                                    u16* __restrict__ QKb,
                                                    u16* __restrict__ Vtg,
                                                    const u16* __restrict__ Av,
                                                    const u16* __restrict__ Wv,
                                                    const float* __restrict__ bv,
                                                    u16* __restrict__ Cv) {
    __shared__ u16 As[128 * 32];
    __shared__ u16 Bs[128 * 32];
    const int K = 256;
    int tid = threadIdx.x;
    int bid = blockIdx.x;
    int w = tid >> 6, lane = tid & 63, quad = lane >> 4, l15 = lane & 15;
    int wm = (w & 1) * 64, wn = (w >> 1) * 64;
    int isval = bid < 1360;
    int bm, bn;
    const u16 *A, *W;
    const float* bp;
    if (isval) {
        bm = (bid % 680) * 128; bn = (bid / 680) * 128;
        A = Av; W = Wv; bp = bv;
    } else {
        int id = bid - 1360;
        bm = (id & 127) * 128;
        int by = id >> 7;
        bn = by * 128;
        A = (by < 4) ? A0 : A1;
        W = Wt; bp = bias;
    }
    int r0 = tid >> 2;
    int c0 = ((tid & 3) ^ ((tid >> 3) & 3)) * 8;
    const u16* ga0 = A + (size_t)(bm + r0) * K + c0;
    const u16* ga1 = ga0 + (size_t)64 * K;
    const u16* gb0 = W + (size_t)(bn + r0) * K + c0;
    const u16* gb1 = gb0 + (size_t)64 * K;
    int abk = (quad ^ ((l15 >> 1) & 3)) * 8;
    f32x4 acc[16];
#pragma unroll
    for (int i = 0; i < 16; ++i) acc[i] = (f32x4){0.f, 0.f, 0.f, 0.f};
    s16x8 ra0 = *(const s16x8*)ga0, ra1 = *(const s16x8*)ga1;
    s16x8 rb0 = *(const s16x8*)gb0, rb1 = *(const s16x8*)gb1;
#pragma unroll 2
    for (int i = 0; i < 8; ++i) {
        *(s16x8*)&As[tid * 8]        = ra0;
        *(s16x8*)&As[2048 + tid * 8] = ra1;
        *(s16x8*)&Bs[tid * 8]        = rb0;
        *(s16x8*)&Bs[2048 + tid * 8] = rb1;
        __syncthreads();
        if (i < 7) {   // reg prefetch: stays in flight across compute (VGPRs cross barriers)
            int k1 = (i + 1) << 5;
            ra0 = *(const s16x8*)(ga0 + k1); ra1 = *(const s16x8*)(ga1 + k1);
            rb0 = *(const s16x8*)(gb0 + k1); rb1 = *(const s16x8*)(gb1 + k1);
        }
        s16x8 af[4], bf[4];
#pragma unroll
        for (int mt = 0; mt < 4; ++mt) af[mt] = *(const s16x8*)&As[(wm + mt * 16 + l15) * 32 + abk];
#pragma unroll
        for (int nt = 0; nt < 4; ++nt) bf[nt] = *(const s16x8*)&Bs[(wn + nt * 16 + l15) * 32 + abk];
#pragma unroll
        for (int mt = 0; mt < 4; ++mt)
#pragma unroll
            for (int nt = 0; nt < 4; ++nt)
                acc[mt * 4 + nt] = __builtin_amdgcn_mfma_f32_16x16x32_bf16(af[mt], bf[nt], acc[mt * 4 + nt], 0, 0, 0);
        __syncthreads();
    }
    float bs[4];
#pragma unroll
    for (int nt = 0; nt < 4; ++nt) bs[nt] = bp[bn + wn + nt * 16 + l15];
    if (isval) {
#pragma unroll
        for (int mt = 0; mt < 4; ++mt) {
            int m = bm + wm + mt * 16 + quad * 4;
#pragma unroll
            for (int nt = 0; nt < 4; ++nt) {
                int n = bn + wn + nt * 16 + l15;
#pragma unroll
                for (int r = 0; r < 4; ++r)
                    Cv[(size_t)(m + r) * 256 + n] = f2b(acc[mt * 4 + nt][r] + bs[nt]);
            }
        }
    } else if (bn < 512) {
        float qs = (bn + wn < 256) ? 0.25506734f : 1.0f;  // Q cols pre-scaled for exp2 softmax
#pragma unroll
        for (int mt = 0; mt < 4; ++mt) {
            int m = bm + wm + mt * 16 + quad * 4;
#pragma unroll
            for (int nt = 0; nt < 4; ++nt) {
                int n = bn + wn + nt * 16 + l15;
#pragma unroll
                for (int r = 0; r < 4; ++r)
                    QKb[(size_t)(m + r) * 512 + n] = f2b((acc[mt * 4 + nt][r] + bs[nt]) * qs);
            }
        }
    } else {
#pragma unroll
        for (int mt = 0; mt < 4; ++mt) {
            int m = bm + wm + mt * 16 + quad * 4;
            int b = m >> 10, t = m & 1023;
#pragma unroll
            for (int nt = 0; nt < 4; ++nt) {
                int nv = bn + wn + nt * 16 + l15 - 512;
                int h = nv >> 5, dh = nv & 31;
                u16x4 o;
#pragma unroll
                for (int r = 0; r < 4; ++r) o[r] = f2b(acc[mt * 4 + nt][r] + bs[nt]);
                *(u16x4*)(Vtg + (((size_t)(b * 8 + h) * 32 + dh) << 10) + t) = o;
            }
        }
    }
}

// ================= MFMA GEMM, 128x128 tile, reg-prefetch staging =====================
template <int RELU, int OUTBF>
__global__ __launch_bounds__(256) void gemm128(const u16* __restrict__ A,
                                               const u16* __restrict__ Wt,
                                               const float* __restrict__ bias,
                                               float* __restrict__ Cf,
                                               u16* __restrict__ Cb,
                                               int M, int N, int K) {
    __shared__ u16 As[128 * 32];
    __shared__ u16 Bs[128 * 32];
    int tid = threadIdx.x;
    int bm = blockIdx.x * 128, bn = blockIdx.y * 128;
    int w = tid >> 6, lane = tid & 63, quad = lane >> 4, l15 = lane & 15;
    int wm = (w & 1) * 64, wn = (w >> 1) * 64;
    int r0 = tid >> 2;
    int c0 = ((tid & 3) ^ ((tid >> 3) & 3)) * 8;
    const u16* ga0 = A  + (size_t)(bm + r0) * K + c0;
    const u16* ga1 = ga0 + (size_t)64 * K;
    const u16* gb0 = Wt + (size_t)(bn + r0) * K + c0;
    const u16* gb1 = gb0 + (size_t)64 * K;
    int abk = (quad ^ ((l15 >> 1) & 3)) * 8;
    f32x4 acc[16];
#pragma unroll
    for (int i = 0; i < 16; ++i) acc[i] = (f32x4){0.f, 0.f, 0.f, 0.f};
    s16x8 ra0 = *(const s16x8*)ga0, ra1 = *(const s16x8*)ga1;
    s16x8 rb0 = *(const s16x8*)gb0, rb1 = *(const s16x8*)gb1;
    int nk = K >> 5;
#pragma unroll 2
    for (int i = 0; i < nk; ++i) {
        *(s16x8*)&As[tid * 8]        = ra0;
        *(s16x8*)&As[2048 + tid * 8] = ra1;
        *(s16x8*)&Bs[tid * 8]        = rb0;
        *(s16x8*)&Bs[2048 + tid * 8] = rb1;
        __syncthreads();
        if (i + 1 < nk) {
            int k1 = (i + 1) << 5;
            ra0 = *(const s16x8*)(ga0 + k1); ra1 = *(const s16x8*)(ga1 + k1);
            rb0 = *(const s16x8*)(gb0 + k1); rb1 = *(const s16x8*)(gb1 + k1);
        }
        s16x8 af[4], bf[4];
#pragma unroll
        for (int mt = 0; mt < 4; ++mt) af[mt] = *(const s16x8*)&As[(wm + mt * 16 + l15) * 32 + abk];
#pragma unroll
        for (int nt = 0; nt < 4; ++nt) bf[nt] = *(const s16x8*)&Bs[(wn + nt * 16 + l15) * 32 + abk];
#pragma unroll
        for (int mt = 0; mt < 4; ++mt)
#pragma unroll
            for (int nt = 0; nt < 4; ++nt)
                acc[mt * 4 + nt] = __builtin_amdgcn_mfma_f32_16x16x32_bf16(af[mt], bf[nt], acc[mt * 4 + nt], 0, 0, 0);
        __syncthreads();
    }
    float bs[4];
#pragma unroll
    for (int nt = 0; nt < 4; ++nt) bs[nt] = bias[bn + wn + nt * 16 + l15];
#pragma unroll
    for (int mt = 0; mt < 4; ++mt) {
        int m = bm + wm + mt * 16 + quad * 4;
#pragma unroll
        for (int nt = 0; nt < 4; ++nt) {
            int n = bn + wn + nt * 16 + l15;
#pragma unroll
            for (int r = 0; r < 4; ++r) {
                float v = acc[mt * 4 + nt][r] + bs[nt];
                if (RELU) v = fmaxf(v, 0.f);
                if (OUTBF) Cb[(size_t)(m + r) * N + n] = f2b(v);
                else       Cf[(size_t)(m + r) * N + n] = v;
            }
        }
    }
}

// ================= MFMA GEMM, 64x128 tile, reg-prefetch staging ======================
template <int RELU, int OUTBF>
__global__ __launch_bounds__(256) void gemm64(const u16* __restrict__ A,
                                              const u16* __restrict__ Wt,
                                              const float* __restrict__ bias,
                                              float* __restrict__ Cf,
                                              u16* __restrict__ Cb,
                                              int M, int N, int K) {
    __shared__ u16 As[64 * 32];
    __shared__ u16 Bs[128 * 32];
    int tid = threadIdx.x;
    int bm = blockIdx.x * 64, bn = blockIdx.y * 128;
    int w = tid >> 6, lane = tid & 63, quad = lane >> 4, l15 = lane & 15;
    int wn = w * 32;
    int r0 = tid >> 2;
    int c0 = ((tid & 3) ^ ((tid >> 3) & 3)) * 8;
    const u16* ga0 = A  + (size_t)(bm + r0) * K + c0;
    const u16* gb0 = Wt + (size_t)(bn + r0) * K + c0;
    const u16* gb1 = gb0 + (size_t)64 * K;
    int abk = (quad ^ ((l15 >> 1) & 3)) * 8;
    f32x4 acc[8];
#pragma unroll
    for (int i = 0; i < 8; ++i) acc[i] = (f32x4){0.f, 0.f, 0.f, 0.f};
    s16x8 ra0 = *(const s16x8*)ga0;
    s16x8 rb0 = *(const s16x8*)gb0, rb1 = *(const s16x8*)gb1;
    int nk = K >> 5;
#pragma unroll 2
    for (int i = 0; i < nk; ++i) {
        *(s16x8*)&As[tid * 8]        = ra0;
        *(s16x8*)&Bs[tid * 8]        = rb0;
        *(s16x8*)&Bs[2048 + tid * 8] = rb1;
        __syncthreads();
        if (i + 1 < nk) {
            int k1 = (i + 1) << 5;
            ra0 = *(const s16x8*)(ga0 + k1);
            rb0 = *(const s16x8*)(gb0 + k1); rb1 = *(const s16x8*)(gb1 + k1);
        }
        s16x8 af[4], bf[2];
#pragma unroll
        for (int mt = 0; mt < 4; ++mt) af[mt] = *(const s16x8*)&As[(mt * 16 + l15) * 32 + abk];
#pragma unroll
        for (int nt = 0; nt < 2; ++nt) bf[nt] = *(const s16x8*)&Bs[(wn + nt * 16 + l15) * 32 + abk];
#pragma unroll
        for (int mt = 0; mt < 4; ++mt)
#pragma unroll
            for (int nt = 0; nt < 2; ++nt)
                acc[mt * 2 + nt] = __builtin_amdgcn_mfma_f32_16x16x32_bf16(af[mt], bf[nt], acc[mt * 2 + nt], 0, 0, 0);
        __syncthreads();
    }
    float bs[2];
#pragma unroll
    for (int nt = 0; nt < 2; ++nt) bs[nt] = bias[bn + wn + nt * 16 + l15];
#pragma unroll
    for (int mt = 0; mt < 4; ++mt) {
        int m = bm + mt * 16 + quad * 4;
#pragma unroll
        for (int nt = 0; nt < 2; ++nt) {
            int n = bn + wn + nt * 16 + l15;
#pragma unroll
            for (int r = 0; r < 4; ++r) {
                float v = acc[mt * 2 + nt][r] + bs[nt];
                if (RELU) v = fmaxf(v, 0.f);
                if (OUTBF) Cb[(size_t)(m + r) * N + n] = f2b(v);
                else       Cf[(size_t)(m + r) * N + n] = v;
            }
        }
    }
}

// ---------------- MFMA flash attention, standalone (low VGPR -> high occupancy) ----------
// XOR-swizzled LDS (conflict-free b128 phases, verified round 2); softmax denominator via
// ones-column MFMA (o2) instead of VALU lsum + shuffles.
__global__ __launch_bounds__(256) void attn_sw(const u16* __restrict__ QK,
                                               const u16* __restrict__ Vt,
                                               u16* __restrict__ O) {
    __shared__ __align__(16) u16 smem[8192];   // 16 KB: Ks 4K + Vs 4K + Ps 8K (bytes)
    int tid = threadIdx.x, w = tid >> 6, lane = tid & 63, quad = lane >> 4, l15 = lane & 15;
    u16* Ks  = smem;                       // [64 key][32 dh], chunk(16B) ^= (row>>1)&3
    u16* Vs  = smem + 2048;                // [32 dh][64 key], chunk(16B) ^= row&7
    u16* Psw = smem + 4096 + w * 1024;     // [16 q][64 key], chunk ^= q&7, 8B slot preserved
    int id = blockIdx.x;
    int qt = id & 15, bh = id >> 4;
    int h = bh & 7, b = bh >> 3;
    int qbase = qt * 64 + w * 16;
    s16x8 qf = *(const s16x8*)(QK + (size_t)(b * cLQ + qbase + l15) * 512 + h * 32 + quad * 8);
    f32x4 o0 = {0.f,0.f,0.f,0.f}, o1 = {0.f,0.f,0.f,0.f}, o2 = {0.f,0.f,0.f,0.f};
    int skey = tid >> 2, kchunk = tid & 3;
    int ks_off = skey * 32 + ((kchunk ^ ((skey >> 1) & 3)) * 8);   // swizzled store addr
    int sdh = kchunk * 8;
    int vdh = tid >> 3, vchunk = tid & 7;
    int vs_off = vdh * 64 + ((vchunk ^ (vdh & 7)) * 8);
    int vkc = vchunk * 8;
    int ksw = (l15 >> 1) & 3;   // Ks read swizzle ((row>>1)&3, t*16 contributes 0)
    int vsw = l15 & 7;          // Vs/Ps read swizzle (row&7; +16 rows identical)
    size_t kgbase = (size_t)(b * cLQ) * 512 + 256 + h * 32;
    size_t vgbase = (size_t)bh * 32 * cLQ;
    s16x8 kreg = *(const s16x8*)(QK + kgbase + (size_t)skey * 512 + sdh);
    s16x8 vreg = *(const s16x8*)(Vt + vgbase + (size_t)vdh * cLQ + vkc);
    const s16x8 ones = {16256,16256,16256,16256,16256,16256,16256,16256};  // bf16 1.0 x8
    for (int kt = 0; kt < cLQ; kt += 64) {
        __syncthreads();
        *(s16x8*)&Ks[ks_off] = kreg;
        *(s16x8*)&Vs[vs_off] = vreg;
        if (kt + 64 < cLQ) {
            kreg = *(const s16x8*)(QK + kgbase + (size_t)(kt + 64 + skey) * 512 + sdh);
            vreg = *(const s16x8*)(Vt + vgbase + (size_t)vdh * cLQ + kt + 64 + vkc);
        }
        __syncthreads();
#pragma unroll
        for (int t = 0; t < 4; ++t) {
            s16x8 kf = *(const s16x8*)&Ks[(t * 16 + l15) * 32 + (quad ^ ksw) * 8];
            f32x4 z = {0.f,0.f,0.f,0.f};
            f32x4 sc = __builtin_amdgcn_mfma_f32_16x16x32_bf16(kf, qf, z, 0, 0, 0);
            u16x4 pb;
#pragma unroll
            for (int r = 0; r < 4; ++r) pb[r] = f2b(exp2f(sc[r]));   // scale baked into Q
            *(u16x4*)&Psw[l15 * 64 + (((t * 2 + (quad >> 1)) ^ vsw) * 8) + (quad & 1) * 4] = pb;
        }
#pragma unroll
        for (int ks = 0; ks < 2; ++ks) {
            int coff = ((ks * 4 + quad) ^ vsw) * 8;
            s16x8 pa  = *(const s16x8*)&Psw[l15 * 64 + coff];
            s16x8 vb0 = *(const s16x8*)&Vs[l15 * 64 + coff];
            s16x8 vb1 = *(const s16x8*)&Vs[(l15 + 16) * 64 + coff];
            o0 = __builtin_amdgcn_mfma_f32_16x16x32_bf16(pa, vb0, o0, 0, 0, 0);
            o1 = __builtin_amdgcn_mfma_f32_16x16x32_bf16(pa, vb1, o1, 0, 0, 0);
            o2 = __builtin_amdgcn_mfma_f32_16x16x32_bf16(pa, ones, o2, 0, 0, 0);  // lsum on matrix pipe
        }
    }
#pragma unroll
    for (int r = 0; r < 4; ++r) {
        float inv = 1.0f / o2[r];   // per-q denominator, already in-lane: no shuffles
        int q = qbase + quad * 4 + r;
        size_t ob = (size_t)(b * cLQ + q) * cD + h * 32;
        O[ob + l15]      = f2b(o0[r] * inv);
        O[ob + 16 + l15] = f2b(o1[r] * inv);
    }
}

// ---------------- fused residual add + LayerNorm (1 wave per 256-row) ----------------
template <int WB, int QP>
__global__ __launch_bounds__(256) void add_ln_kernel(const float* __restrict__ X,
                                                     const float* __restrict__ R,
                                                     const float* __restrict__ g,
                                                     const float* __restrict__ bt,
                                                     const float* __restrict__ qp,
                                                     float* __restrict__ out,
                                                     u16* __restrict__ outb) {
    int wave = threadIdx.x / 64;
    int lane = threadIdx.x % 64;
    int row = blockIdx.x * 4 + wave;
    const float* x = X + (size_t)row * cD;
    const float* r = R + (size_t)row * cD;
    float4 xv = *(const float4*)(x + lane * 4);
    float4 rv = *(const float4*)(r + lane * 4);
    float v0 = xv.x + rv.x, v1 = xv.y + rv.y, v2 = xv.z + rv.z, v3 = xv.w + rv.w;
    float s = v0 + v1 + v2 + v3;
    float s2 = v0 * v0 + v1 * v1 + v2 * v2 + v3 * v3;
#pragma unroll
    for (int off = 32; off > 0; off >>= 1) {
        s += __shfl_xor(s, off);
        s2 += __shfl_xor(s2, off);
    }
    float mean = s * (1.0f / 256.0f);
    float var = s2 * (1.0f / 256.0f) - mean * mean;
    float rstd = rsqrtf(var + 1e-5f);
    float4 gv = *(const float4*)(g + lane * 4);
    float4 bv = *(const float4*)(bt + lane * 4);
    float4 o;
    o.x = (v0 - mean) * rstd * gv.x + bv.x;
    o.y = (v1 - mean) * rstd * gv.y + bv.y;
    o.z = (v2 - mean) * rstd * gv.z + bv.z;
    o.w = (v3 - mean) * rstd * gv.w + bv.w;
    *(float4*)(out + (size_t)row * cD + lane * 4) = o;
    if (WB) {
        u16x4 ob = { f2b(o.x), f2b(o.y), f2b(o.z), f2b(o.w) };
        *(u16x4*)(outb + (size_t)row * cD + lane * 4) = ob;
    }
    if (QP) {
        float4 qv = *(const float4*)(qp + (size_t)row * cD + lane * 4);
        u16x4 ob = { f2b(o.x + qv.x), f2b(o.y + qv.y), f2b(o.z + qv.z), f2b(o.w + qv.w) };
        *(u16x4*)(outb + (size_t)row * cD + lane * 4) = ob;
    }
}

// ------- ms-deform-attn sampling: 8 lanes per (b,q,h); off+attw fused (width 384)
__global__ __launch_bounds__(256) void deform_kernel(const u16* __restrict__ value,
                                                     const float* __restrict__ oa,
                                                     const float* __restrict__ refp,
                                                     u16* __restrict__ out) {
    int t = blockIdx.x * 32 + (threadIdx.x >> 3);
    int dq = threadIdx.x & 7;
    int h = t & 7;
    int bq = t >> 3;
    int b = bq >> 10;
    const float* al = oa + (size_t)bq * 384 + 256 + h * 16;
    float wv[16];
    float mx = -1e30f;
#pragma unroll
    for (int i = 0; i < 16; ++i) { wv[i] = al[i]; mx = fmaxf(mx, wv[i]); }
    float sum = 0.f;
#pragma unroll
    for (int i = 0; i < 16; ++i) { wv[i] = __expf(wv[i] - mx); sum += wv[i]; }
    float inv = 1.f / sum;
    const float* off = oa + (size_t)bq * 384 + h * 32;
    const float* rp = refp + (size_t)bq * 8;
    const u16* vb = value + ((size_t)b * cLVTOT) * 256 + h * 32 + dq * 4;
    const int starts[4] = {0, 4096, 5120, 5376};
    const int dims[4] = {64, 32, 16, 8};
    float a0 = 0.f, a1 = 0.f, a2 = 0.f, a3 = 0.f;
#pragma unroll
    for (int l = 0; l < 4; ++l) {
        int hl = dims[l], wl = dims[l];
        float rx = rp[l * 2 + 0], ry = rp[l * 2 + 1];
#pragma unroll
        for (int p = 0; p < 4; ++p) {
            float ox = off[(l * 4 + p) * 2 + 0];
            float oy = off[(l * 4 + p) * 2 + 1];
            float x = rx * (float)wl + ox - 0.5f;
            float y = ry * (float)hl + oy - 0.5f;
            float x0f = floorf(x), y0f = floorf(y);
            float lx = x - x0f, ly = y - y0f;
            int x0 = (int)x0f, y0 = (int)y0f;
            float aw = wv[l * 4 + p] * inv;
            float cw[4] = {(1.f - lx) * (1.f - ly), lx * (1.f - ly),
                           (1.f - lx) * ly, lx * ly};
            int xs[4] = {x0, x0 + 1, x0, x0 + 1};
            int ys[4] = {y0, y0, y0 + 1, y0 + 1};
#pragma unroll
            for (int c = 0; c < 4; ++c) {
                int xi = xs[c], yi = ys[c];
                bool valid = (xi >= 0) && (xi < wl) && (yi >= 0) && (yi < hl);
                int xc = min(max(xi, 0), wl - 1);
                int yc = min(max(yi, 0), hl - 1);
                int idx = starts[l] + yc * wl + xc;
                float wgt = valid ? aw * cw[c] : 0.f;
                unsigned long long u = *(const unsigned long long*)(vb + (size_t)idx * 256);
                a0 += wgt * bl((unsigned)(u & 0xffffull));
                a1 += wgt * bl((unsigned)((u >> 16) & 0xffffull));
                a2 += wgt * bl((unsigned)((u >> 32) & 0xffffull));
                a3 += wgt * bl((unsigned)(u >> 48));
            }
        }
    }
    u16x4 o = { f2b(a0), f2b(a1), f2b(a2), f2b(a3) };
    *(u16x4*)(out + (size_t)bq * 256 + h * 32 + dq * 4) = o;
}

extern "C" void kernel_launch(void* const* d_in, const int* in_sizes, int n_in,
                              void* d_out, int out_size, void* d_ws, size_t ws_size,
                              hipStream_t stream) {
    const float* tgt        = (const float*)d_in[0];
    const float* query_pos  = (const float*)d_in[1];
    const float* refp       = (const float*)d_in[2];
    const float* src        = (const float*)d_in[3];
    const float* in_proj_w  = (const float*)d_in[4];
    const float* in_proj_b  = (const float*)d_in[5];
    const float* out_proj_b = (const float*)d_in[7];
    const float* norm2_g    = (const float*)d_in[8];
    const float* norm2_b    = (const float*)d_in[9];
    const float* value_b    = (const float*)d_in[11];
    const float* off_b      = (const float*)d_in[13];
    const float* attw_b     = (const float*)d_in[15];
    const float* outp_b     = (const float*)d_in[17];
    const float* norm1_g    = (const float*)d_in[18];
    const float* norm1_b    = (const float*)d_in[19];
    const float* lin1_b     = (const float*)d_in[21];
    const float* lin2_b     = (const float*)d_in[23];
    const float* norm3_g    = (const float*)d_in[24];
    const float* norm3_b    = (const float*)d_in[25];

    char* W = (char*)d_ws;
    const size_t S84 = 8388608;   // 16384*256*2 B
    u16*   tgtb  = (u16*)(W + 0);
    u16*   q2b   = (u16*)(W + 0);
    u16*   qb    = (u16*)(W + 1 * S84);
    u16*   QKb   = (u16*)(W + 2 * S84);         // slots 2-3
    u16*   dtb   = (u16*)(W + 2 * S84);
    u16*   x2b   = (u16*)(W + 3 * S84);
    float* ffn2f = (float*)(W + 4 * S84);       // slots 4-5
    u16*   aob   = (u16*)(W + 5 * S84);
    float* oaf   = (float*)(W + 5 * S84);       // slots 5-7
    u16*   Vtg   = (u16*)(W + 6 * S84);
    float* t2f   = (float*)(W + 6 * S84);       // slots 6-7
    float* x1f   = (float*)(W + 8 * S84);
    float* x2f   = (float*)(W + 10 * S84);
    u16*   srcb  = (u16*)(W + 12 * S84);
    u16*   ffn1b = (u16*)(W + 12 * S84);
    u16*   valb  = (u16*)(W + 12 * S84 + 44564480);
    char*  wbase = W + 12 * S84 + 2 * 44564480;
    u16* wb_in   = (u16*)(wbase + 0);
    u16* wb_out  = (u16*)(wbase + 393216);
    u16* wb_val  = (u16*)(wbase + 524288);
    u16* wb_off  = (u16*)(wbase + 655360);      // off(256) + attw(128) rows contiguous
    u16* wb_outp = (u16*)(wbase + 851968);
    u16* wb_lin1 = (u16*)(wbase + 983040);
    u16* wb_lin2 = (u16*)(wbase + 1507328);
    float* biasoa= (float*)(wbase + 2031616);
    float* out = (float*)d_out;

    dim3 blk(256);

    // single fused conversion pass (tgt/qb + src + weights + bias concat)
    WArgs wa;
    wa.src[0] = (const float4*)in_proj_w;  wa.src[1] = (const float4*)d_in[6];
    wa.src[2] = (const float4*)d_in[10];   wa.src[3] = (const float4*)d_in[12];
    wa.src[4] = (const float4*)d_in[14];   wa.src[5] = (const float4*)d_in[16];
    wa.src[6] = (const float4*)d_in[20];   wa.src[7] = (const float4*)d_in[22];
    prep_all<<<dim3(6713), blk, 0, stream>>>((const float4*)tgt, (const float4*)query_pos,
                                             (u16x8*)tgtb, (u16x8*)qb,
                                             (const float4*)src, (u16x8*)srcb,
                                             wa, (u16x8*)wb_in, off_b, attw_b, biasoa);

    // QKV projection + value projection in one uniform grid (1360 val + 768 qkv blocks)
    gemm_qkv_val<<<dim3(2128), blk, 0, stream>>>(qb, tgtb, wb_in, in_proj_b, QKb, Vtg,
                                                 srcb, wb_val, value_b, valb);
    // MHA attention (standalone, low VGPR)
    attn_sw<<<dim3(cB * cH * 16), blk, 0, stream>>>(QKb, Vtg, aob);
    gemm64<0, 0><<<dim3(256, 2), blk, 0, stream>>>(aob, wb_out, out_proj_b, t2f, nullptr, cNTOK, 256, 256);
    add_ln_kernel<0, 1><<<dim3(4096), blk, 0, stream>>>(tgt, t2f, norm2_g, norm2_b, query_pos, x1f, q2b);

    // deformable attention (value projection already done above)
    gemm64<0, 0><<<dim3(256, 3), blk, 0, stream>>>(q2b, wb_off, biasoa, oaf, nullptr, cNTOK, 384, 256);
    deform_kernel<<<dim3(4096), blk, 0, stream>>>(valb, oaf, refp, dtb);
    gemm64<0, 0><<<dim3(256, 2), blk, 0, stream>>>(dtb, wb_outp, outp_b, t2f, nullptr, cNTOK, 256, 256);
    add_ln_kernel<1, 0><<<dim3(4096), blk, 0, stream>>>(x1f, t2f, norm1_g, norm1_b, nullptr, x2f, x2b);

    // FFN
    gemm128<1, 1><<<dim3(128, 8), blk, 0, stream>>>(x2b, wb_lin1, lin1_b, nullptr, ffn1b, cNTOK, 1024, 256);
    gemm64<0, 0><<<dim3(256, 2), blk, 0, stream>>>(ffn1b, wb_lin2, lin2_b, ffn2f, nullptr, cNTOK, 256, 1024);
    add_ln_kernel<0, 0><<<dim3(4096), blk, 0, stream>>>(x2f, ffn2f, norm3_g, norm3_b, nullptr, out, nullptr);
}

// Round 5
// 425.574 us; speedup vs baseline: 1.0355x; 1.0355x over previous
//
#include <hip/hip_runtime.h>
#include <math.h>

typedef short s16x8 __attribute__((ext_vector_type(8)));
typedef float f32x4 __attribute__((ext_vector_type(4)));
typedef unsigned short u16;
typedef unsigned short u16x4 __attribute__((ext_vector_type(4)));
typedef unsigned short u16x8 __attribute__((ext_vector_type(8)));

constexpr int cB    = 16;
constexpr int cLQ   = 1024;
constexpr int cD    = 256;
constexpr int cH    = 8;
constexpr int cLVTOT= 5440;
constexpr int cNTOK = cB * cLQ;    // 16384
constexpr int cNV   = cB * cLVTOT; // 87040

__device__ __forceinline__ u16 f2b(float f) {
    __bf16 h = (__bf16)f;
    u16 u;
    __builtin_memcpy(&u, &h, 2);
    return u;
}
__device__ __forceinline__ float bl(unsigned x) {
    return __uint_as_float(x << 16);
}
__device__ __forceinline__ u16x8 cvt8(float4 a, float4 b) {
    return (u16x8){ f2b(a.x), f2b(a.y), f2b(a.z), f2b(a.w),
                    f2b(b.x), f2b(b.y), f2b(b.z), f2b(b.w) };
}

// ===== fused conversion pass: tgt/qb + all 8 weight tensors + bias concat =====
// src conversion REMOVED (value GEMM reads f32 src directly): prep traffic drops
// ~190 MB -> ~66 MB, shrinking the window that contends with the harness's
// workspace-poison fill (6.8 TB/s co-runner, round 3/4 evidence).
// Block segments: [0,1024) tgt/qb | [1024,1272) weights | 1272 bias.
struct WArgs { const float4* src[8]; };
__global__ __launch_bounds__(256) void prep_all(const float4* __restrict__ t,
                                                const float4* __restrict__ q,
                                                u16x8* __restrict__ tb,
                                                u16x8* __restrict__ qb,
                                                WArgs wa,
                                                u16x8* __restrict__ wout,
                                                const float* __restrict__ off_b,
                                                const float* __restrict__ attw_b,
                                                float* __restrict__ biasoa) {
    int bid = blockIdx.x;
    if (bid < 1024) {
        size_t u = (size_t)bid * 256 + threadIdx.x;   // 16-f32 unit over 16384x256 tgt
        const float4* tp = t + u * 4;
        const float4* qp = q + u * 4;
        float4 a0 = tp[0], a1 = tp[1], a2 = tp[2], a3 = tp[3];
        float4 b0 = qp[0], b1 = qp[1], b2 = qp[2], b3 = qp[3];
        tb[u * 2]     = cvt8(a0, a1);
        tb[u * 2 + 1] = cvt8(a2, a3);
        float4 s0 = {a0.x + b0.x, a0.y + b0.y, a0.z + b0.z, a0.w + b0.w};
        float4 s1 = {a1.x + b1.x, a1.y + b1.y, a1.z + b1.z, a1.w + b1.w};
        float4 s2 = {a2.x + b2.x, a2.y + b2.y, a2.z + b2.z, a2.w + b2.w};
        float4 s3 = {a3.x + b3.x, a3.y + b3.y, a3.z + b3.z, a3.w + b3.w};
        qb[u * 2]     = cvt8(s0, s1);
        qb[u * 2 + 1] = cvt8(s2, s3);
    } else if (bid < 1272) {
        int u = (bid - 1024) * 256 + threadIdx.x;   // 16-f32 unit over concat'd weights
        int i = u * 4;                               // float4 index; boundaries %4==0
        int s, off;
        if (i < 98304) {
            if (i < 65536) { if (i < 49152) { s = 0; off = i; } else { s = 1; off = i - 49152; } }
            else           { if (i < 81920) { s = 2; off = i - 65536; } else { s = 3; off = i - 81920; } }
        } else {
            if (i < 122880){ if (i < 106496){ s = 4; off = i - 98304; } else { s = 5; off = i - 106496; } }
            else           { if (i < 188416){ s = 6; off = i - 122880; } else { s = 7; off = i - 188416; } }
        }
        const float4* wp = wa.src[s] + off;
        float4 a0 = wp[0], a1 = wp[1], a2 = wp[2], a3 = wp[3];
        wout[(size_t)u * 2]     = cvt8(a0, a1);
        wout[(size_t)u * 2 + 1] = cvt8(a2, a3);
    } else {
        int tix = threadIdx.x;
        biasoa[tix] = off_b[tix];
        if (tix < 128) biasoa[256 + tix] = attw_b[tix];
    }
}

// ===== fused QKV projection + value projection (one grid, identical 128x128xK256 blocks) =====
// bid < 1360: value projection — A staged DIRECTLY from f32 src (reg cvt to bf16 before
// ds_write; no srcb intermediate).  bid >= 1360: QKV (qb/tgtb bf16 @ in_proj).
__global__ __launch_bounds__(256) void gemm_qkv_val(const u16* __restrict__ A0,
                                                    const u16* __restrict__ A1,
                                                    const u16* __restrict__ Wt,
                                                    const float* __restrict__ bias,
                                                    u16* __restrict__ QKb,
                                                    u16* __restrict__ Vtg,
                                                    const float* __restrict__ Av,
                                                    const u16* __restrict__ Wv,
                                                    const float* __restrict__ bv,
                                                    u16* __restrict__ Cv) {
    __shared__ u16 As[128 * 32];
    __shared__ u16 Bs[128 * 32];
    const int K = 256;
    int tid = threadIdx.x;
    int bid = blockIdx.x;
    int w = tid >> 6, lane = tid & 63, quad = lane >> 4, l15 = lane & 15;
    int wm = (w & 1) * 64, wn = (w >> 1) * 64;
    int r0 = tid >> 2;
    int c0 = ((tid & 3) ^ ((tid >> 3) & 3)) * 8;
    int abk = (quad ^ ((l15 >> 1) & 3)) * 8;
    f32x4 acc[16];
#pragma unroll
    for (int i = 0; i < 16; ++i) acc[i] = (f32x4){0.f, 0.f, 0.f, 0.f};

    if (bid < 1360) {
        // ---------------- value projection, f32-A staging ----------------
        int bm = (bid >> 1) * 128, bn = (bid & 1) * 128;   // bn pairs adjacent: A-tile L2/L3 reuse
        const float* ga0 = Av + (size_t)(bm + r0) * 256 + c0;
        const float* ga1 = ga0 + (size_t)64 * 256;
        const u16* gb0 = Wv + (size_t)(bn + r0) * 256 + c0;
        const u16* gb1 = gb0 + (size_t)64 * 256;
        float4 ra0a = *(const float4*)ga0, ra0b = *(const float4*)(ga0 + 4);
        float4 ra1a = *(const float4*)ga1, ra1b = *(const float4*)(ga1 + 4);
        s16x8 rb0 = *(const s16x8*)gb0, rb1 = *(const s16x8*)gb1;
#pragma unroll 2
        for (int i = 0; i < 8; ++i) {
            *(u16x8*)&As[tid * 8]        = cvt8(ra0a, ra0b);
            *(u16x8*)&As[2048 + tid * 8] = cvt8(ra1a, ra1b);
            *(s16x8*)&Bs[tid * 8]        = rb0;
            *(s16x8*)&Bs[2048 + tid * 8] = rb1;
            __syncthreads();
            if (i < 7) {
                int k1 = (i + 1) << 5;
                ra0a = *(const float4*)(ga0 + k1); ra0b = *(const float4*)(ga0 + k1 + 4);
                ra1a = *(const float4*)(ga1 + k1); ra1b = *(const float4*)(ga1 + k1 + 4);
                rb0  = *(const s16x8*)(gb0 + k1);  rb1  = *(const s16x8*)(gb1 + k1);
            }
            s16x8 af[4], bf[4];
#pragma unroll
            for (int mt = 0; mt < 4; ++mt) af[mt] = *(const s16x8*)&As[(wm + mt * 16 + l15) * 32 + abk];
#pragma unroll
            for (int nt = 0; nt < 4; ++nt) bf[nt] = *(const s16x8*)&Bs[(wn + nt * 16 + l15) * 32 + abk];
#pragma unroll
            for (int mt = 0; mt < 4; ++mt)
#pragma unroll
                for (int nt = 0; nt < 4; ++nt)
                    acc[mt * 4 + nt] = __builtin_amdgcn_mfma_f32_16x16x32_bf16(af[mt], bf[nt], acc[mt * 4 + nt], 0, 0, 0);
            __syncthreads();
        }
        float bs[4];
#pragma unroll
        for (int nt = 0; nt < 4; ++nt) bs[nt] = bv[bn + wn + nt * 16 + l15];
#pragma unroll
        for (int mt = 0; mt < 4; ++mt) {
            int m = bm + wm + mt * 16 + quad * 4;
#pragma unroll
            for (int nt = 0; nt < 4; ++nt) {
                int n = bn + wn + nt * 16 + l15;
#pragma unroll
                for (int r = 0; r < 4; ++r)
                    Cv[(size_t)(m + r) * 256 + n] = f2b(acc[mt * 4 + nt][r] + bs[nt]);
            }
        }
        return;
    }
    // ---------------- QKV projection, bf16 staging ----------------
    int id = bid - 1360;
    int bm = (id & 127) * 128;
    int by = id >> 7;
    int bn = by * 128;
    const u16* A = (by < 4) ? A0 : A1;
    const u16* ga0 = A + (size_t)(bm + r0) * K + c0;
    const u16* ga1 = ga0 + (size_t)64 * K;
    const u16* gb0 = Wt + (size_t)(bn + r0) * K + c0;
    const u16* gb1 = gb0 + (size_t)64 * K;
    s16x8 ra0 = *(const s16x8*)ga0, ra1 = *(const s16x8*)ga1;
    s16x8 rb0 = *(const s16x8*)gb0, rb1 = *(const s16x8*)gb1;
#pragma unroll 2
    for (int i = 0; i < 8; ++i) {
        *(s16x8*)&As[tid * 8]        = ra0;
        *(s16x8*)&As[2048 + tid * 8] = ra1;
        *(s16x8*)&Bs[tid * 8]        = rb0;
        *(s16x8*)&Bs[2048 + tid * 8] = rb1;
        __syncthreads();
        if (i < 7) {   // reg prefetch: stays in flight across compute
            int k1 = (i + 1) << 5;
            ra0 = *(const s16x8*)(ga0 + k1); ra1 = *(const s16x8*)(ga1 + k1);
            rb0 = *(const s16x8*)(gb0 + k1); rb1 = *(const s16x8*)(gb1 + k1);
        }
        s16x8 af[4], bf[4];
#pragma unroll
        for (int mt = 0; mt < 4; ++mt) af[mt] = *(const s16x8*)&As[(wm + mt * 16 + l15) * 32 + abk];
#pragma unroll
        for (int nt = 0; nt < 4; ++nt) bf[nt] = *(const s16x8*)&Bs[(wn + nt * 16 + l15) * 32 + abk];
#pragma unroll
        for (int mt = 0; mt < 4; ++mt)
#pragma unroll
            for (int nt = 0; nt < 4; ++nt)
                acc[mt * 4 + nt] = __builtin_amdgcn_mfma_f32_16x16x32_bf16(af[mt], bf[nt], acc[mt * 4 + nt], 0, 0, 0);
        __syncthreads();
    }
    float bs[4];
#pragma unroll
    for (int nt = 0; nt < 4; ++nt) bs[nt] = bias[bn + wn + nt * 16 + l15];
    if (bn < 512) {
        float qs = (bn + wn < 256) ? 0.25506734f : 1.0f;  // Q cols pre-scaled for exp2 softmax
#pragma unroll
        for (int mt = 0; mt < 4; ++mt) {
            int m = bm + wm + mt * 16 + quad * 4;
#pragma unroll
            for (int nt = 0; nt < 4; ++nt) {
                int n = bn + wn + nt * 16 + l15;
#pragma unroll
                for (int r = 0; r < 4; ++r)
                    QKb[(size_t)(m + r) * 512 + n] = f2b((acc[mt * 4 + nt][r] + bs[nt]) * qs);
            }
        }
    } else {
#pragma unroll
        for (int mt = 0; mt < 4; ++mt) {
            int m = bm + wm + mt * 16 + quad * 4;
            int b = m >> 10, t = m & 1023;
#pragma unroll
            for (int nt = 0; nt < 4; ++nt) {
                int nv = bn + wn + nt * 16 + l15 - 512;
                int h = nv >> 5, dh = nv & 31;
                u16x4 o;
#pragma unroll
                for (int r = 0; r < 4; ++r) o[r] = f2b(acc[mt * 4 + nt][r] + bs[nt]);
                *(u16x4*)(Vtg + (((size_t)(b * 8 + h) * 32 + dh) << 10) + t) = o;
            }
        }
    }
}

// ================= MFMA GEMM, 128x128 tile, reg-prefetch staging =====================
template <int RELU, int OUTBF>
__global__ __launch_bounds__(256) void gemm128(const u16* __restrict__ A,
                                               const u16* __restrict__ Wt,
                                               const float* __restrict__ bias,
                                               float* __restrict__ Cf,
                                               u16* __restrict__ Cb,
                                               int M, int N, int K) {
    __shared__ u16 As[128 * 32];
    __shared__ u16 Bs[128 * 32];
    int tid = threadIdx.x;
    int bm = blockIdx.x * 128, bn = blockIdx.y * 128;
    int w = tid >> 6, lane = tid & 63, quad = lane >> 4, l15 = lane & 15;
    int wm = (w & 1) * 64, wn = (w >> 1) * 64;
    int r0 = tid >> 2;
    int c0 = ((tid & 3) ^ ((tid >> 3) & 3)) * 8;
    const u16* ga0 = A  + (size_t)(bm + r0) * K + c0;
    const u16* ga1 = ga0 + (size_t)64 * K;
    const u16* gb0 = Wt + (size_t)(bn + r0) * K + c0;
    const u16* gb1 = gb0 + (size_t)64 * K;
    int abk = (quad ^ ((l15 >> 1) & 3)) * 8;
    f32x4 acc[16];
#pragma unroll
    for (int i = 0; i < 16; ++i) acc[i] = (f32x4){0.f, 0.f, 0.f, 0.f};
    s16x8 ra0 = *(const s16x8*)ga0, ra1 = *(const s16x8*)ga1;
    s16x8 rb0 = *(const s16x8*)gb0, rb1 = *(const s16x8*)gb1;
    int nk = K >> 5;
#pragma unroll 2
    for (int i = 0; i < nk; ++i) {
        *(s16x8*)&As[tid * 8]        = ra0;
        *(s16x8*)&As[2048 + tid * 8] = ra1;
        *(s16x8*)&Bs[tid * 8]        = rb0;
        *(s16x8*)&Bs[2048 + tid * 8] = rb1;
        __syncthreads();
        if (i + 1 < nk) {
            int k1 = (i + 1) << 5;
            ra0 = *(const s16x8*)(ga0 + k1); ra1 = *(const s16x8*)(ga1 + k1);
            rb0 = *(const s16x8*)(gb0 + k1); rb1 = *(const s16x8*)(gb1 + k1);
        }
        s16x8 af[4], bf[4];
#pragma unroll
        for (int mt = 0; mt < 4; ++mt) af[mt] = *(const s16x8*)&As[(wm + mt * 16 + l15) * 32 + abk];
#pragma unroll
        for (int nt = 0; nt < 4; ++nt) bf[nt] = *(const s16x8*)&Bs[(wn + nt * 16 + l15) * 32 + abk];
#pragma unroll
        for (int mt = 0; mt < 4; ++mt)
#pragma unroll
            for (int nt = 0; nt < 4; ++nt)
                acc[mt * 4 + nt] = __builtin_amdgcn_mfma_f32_16x16x32_bf16(af[mt], bf[nt], acc[mt * 4 + nt], 0, 0, 0);
        __syncthreads();
    }
    float bs[4];
#pragma unroll
    for (int nt = 0; nt < 4; ++nt) bs[nt] = bias[bn + wn + nt * 16 + l15];
#pragma unroll
    for (int mt = 0; mt < 4; ++mt) {
        int m = bm + wm + mt * 16 + quad * 4;
#pragma unroll
        for (int nt = 0; nt < 4; ++nt) {
            int n = bn + wn + nt * 16 + l15;
#pragma unroll
            for (int r = 0; r < 4; ++r) {
                float v = acc[mt * 4 + nt][r] + bs[nt];
                if (RELU) v = fmaxf(v, 0.f);
                if (OUTBF) Cb[(size_t)(m + r) * N + n] = f2b(v);
                else       Cf[(size_t)(m + r) * N + n] = v;
            }
        }
    }
}

// ================= MFMA GEMM, 64x128 tile, reg-prefetch staging ======================
template <int RELU, int OUTBF>
__global__ __launch_bounds__(256) void gemm64(const u16* __restrict__ A,
                                              const u16* __restrict__ Wt,
                                              const float* __restrict__ bias,
                                              float* __restrict__ Cf,
                                              u16* __restrict__ Cb,
                                              int M, int N, int K) {
    __shared__ u16 As[64 * 32];
    __shared__ u16 Bs[128 * 32];
    int tid = threadIdx.x;
    int bm = blockIdx.x * 64, bn = blockIdx.y * 128;
    int w = tid >> 6, lane = tid & 63, quad = lane >> 4, l15 = lane & 15;
    int wn = w * 32;
    int r0 = tid >> 2;
    int c0 = ((tid & 3) ^ ((tid >> 3) & 3)) * 8;
    const u16* ga0 = A  + (size_t)(bm + r0) * K + c0;
    const u16* gb0 = Wt + (size_t)(bn + r0) * K + c0;
    const u16* gb1 = gb0 + (size_t)64 * K;
    int abk = (quad ^ ((l15 >> 1) & 3)) * 8;
    f32x4 acc[8];
#pragma unroll
    for (int i = 0; i < 8; ++i) acc[i] = (f32x4){0.f, 0.f, 0.f, 0.f};
    s16x8 ra0 = *(const s16x8*)ga0;
    s16x8 rb0 = *(const s16x8*)gb0, rb1 = *(const s16x8*)gb1;
    int nk = K >> 5;
#pragma unroll 2
    for (int i = 0; i < nk; ++i) {
        *(s16x8*)&As[tid * 8]        = ra0;
        *(s16x8*)&Bs[tid * 8]        = rb0;
        *(s16x8*)&Bs[2048 + tid * 8] = rb1;
        __syncthreads();
        if (i + 1 < nk) {
            int k1 = (i + 1) << 5;
            ra0 = *(const s16x8*)(ga0 + k1);
            rb0 = *(const s16x8*)(gb0 + k1); rb1 = *(const s16x8*)(gb1 + k1);
        }
        s16x8 af[4], bf[2];
#pragma unroll
        for (int mt = 0; mt < 4; ++mt) af[mt] = *(const s16x8*)&As[(mt * 16 + l15) * 32 + abk];
#pragma unroll
        for (int nt = 0; nt < 2; ++nt) bf[nt] = *(const s16x8*)&Bs[(wn + nt * 16 + l15) * 32 + abk];
#pragma unroll
        for (int mt = 0; mt < 4; ++mt)
#pragma unroll
            for (int nt = 0; nt < 2; ++nt)
                acc[mt * 2 + nt] = __builtin_amdgcn_mfma_f32_16x16x32_bf16(af[mt], bf[nt], acc[mt * 2 + nt], 0, 0, 0);
        __syncthreads();
    }
    float bs[2];
#pragma unroll
    for (int nt = 0; nt < 2; ++nt) bs[nt] = bias[bn + wn + nt * 16 + l15];
#pragma unroll
    for (int mt = 0; mt < 4; ++mt) {
        int m = bm + mt * 16 + quad * 4;
#pragma unroll
        for (int nt = 0; nt < 2; ++nt) {
            int n = bn + wn + nt * 16 + l15;
#pragma unroll
            for (int r = 0; r < 4; ++r) {
                float v = acc[mt * 2 + nt][r] + bs[nt];
                if (RELU) v = fmaxf(v, 0.f);
                if (OUTBF) Cb[(size_t)(m + r) * N + n] = f2b(v);
                else       Cf[(size_t)(m + r) * N + n] = v;
            }
        }
    }
}

// ---------------- MFMA flash attention, standalone (low VGPR -> high occupancy) ----------
// XOR-swizzled LDS (conflict-free b128 phases, verified round 2); softmax denominator via
// ones-column MFMA (o2) instead of VALU lsum + shuffles.
__global__ __launch_bounds__(256) void attn_sw(const u16* __restrict__ QK,
                                               const u16* __restrict__ Vt,
                                               u16* __restrict__ O) {
    __shared__ __align__(16) u16 smem[8192];   // 16 KB: Ks 4K + Vs 4K + Ps 8K (bytes)
    int tid = threadIdx.x, w = tid >> 6, lane = tid & 63, quad = lane >> 4, l15 = lane & 15;
    u16* Ks  = smem;                       // [64 key][32 dh], chunk(16B) ^= (row>>1)&3
    u16* Vs  = smem + 2048;                // [32 dh][64 key], chunk(16B) ^= row&7
    u16* Psw = smem + 4096 + w * 1024;     // [16 q][64 key], chunk ^= q&7, 8B slot preserved
    int id = blockIdx.x;
    int qt = id & 15, bh = id >> 4;
    int h = bh & 7, b = bh >> 3;
    int qbase = qt * 64 + w * 16;
    s16x8 qf = *(const s16x8*)(QK + (size_t)(b * cLQ + qbase + l15) * 512 + h * 32 + quad * 8);
    f32x4 o0 = {0.f,0.f,0.f,0.f}, o1 = {0.f,0.f,0.f,0.f}, o2 = {0.f,0.f,0.f,0.f};
    int skey = tid >> 2, kchunk = tid & 3;
    int ks_off = skey * 32 + ((kchunk ^ ((skey >> 1) & 3)) * 8);   // swizzled store addr
    int sdh = kchunk * 8;
    int vdh = tid >> 3, vchunk = tid & 7;
    int vs_off = vdh * 64 + ((vchunk ^ (vdh & 7)) * 8);
    int vkc = vchunk * 8;
    int ksw = (l15 >> 1) & 3;   // Ks read swizzle ((row>>1)&3, t*16 contributes 0)
    int vsw = l15 & 7;          // Vs/Ps read swizzle (row&7; +16 rows identical)
    size_t kgbase = (size_t)(b * cLQ) * 512 + 256 + h * 32;
    size_t vgbase = (size_t)bh * 32 * cLQ;
    s16x8 kreg = *(const s16x8*)(QK + kgbase + (size_t)skey * 512 + sdh);
    s16x8 vreg = *(const s16x8*)(Vt + vgbase + (size_t)vdh * cLQ + vkc);
    const s16x8 ones = {16256,16256,16256,16256,16256,16256,16256,16256};  // bf16 1.0 x8
    for (int kt = 0; kt < cLQ; kt += 64) {
        __syncthreads();
        *(s16x8*)&Ks[ks_off] = kreg;
        *(s16x8*)&Vs[vs_off] = vreg;
        if (kt + 64 < cLQ) {
            kreg = *(const s16x8*)(QK + kgbase + (size_t)(kt + 64 + skey) * 512 + sdh);
            vreg = *(const s16x8*)(Vt + vgbase + (size_t)vdh * cLQ + kt + 64 + vkc);
        }
        __syncthreads();
#pragma unroll
        for (int t = 0; t < 4; ++t) {
            s16x8 kf = *(const s16x8*)&Ks[(t * 16 + l15) * 32 + (quad ^ ksw) * 8];
            f32x4 z = {0.f,0.f,0.f,0.f};
            f32x4 sc = __builtin_amdgcn_mfma_f32_16x16x32_bf16(kf, qf, z, 0, 0, 0);
            u16x4 pb;
#pragma unroll
            for (int r = 0; r < 4; ++r) pb[r] = f2b(exp2f(sc[r]));   // scale baked into Q
            *(u16x4*)&Psw[l15 * 64 + (((t * 2 + (quad >> 1)) ^ vsw) * 8) + (quad & 1) * 4] = pb;
        }
#pragma unroll
        for (int ks = 0; ks < 2; ++ks) {
            int coff = ((ks * 4 + quad) ^ vsw) * 8;
            s16x8 pa  = *(const s16x8*)&Psw[l15 * 64 + coff];
            s16x8 vb0 = *(const s16x8*)&Vs[l15 * 64 + coff];
            s16x8 vb1 = *(const s16x8*)&Vs[(l15 + 16) * 64 + coff];
            o0 = __builtin_amdgcn_mfma_f32_16x16x32_bf16(pa, vb0, o0, 0, 0, 0);
            o1 = __builtin_amdgcn_mfma_f32_16x16x32_bf16(pa, vb1, o1, 0, 0, 0);
            o2 = __builtin_amdgcn_mfma_f32_16x16x32_bf16(pa, ones, o2, 0, 0, 0);  // lsum on matrix pipe
        }
    }
#pragma unroll
    for (int r = 0; r < 4; ++r) {
        float inv = 1.0f / o2[r];   // per-q denominator, already in-lane: no shuffles
        int q = qbase + quad * 4 + r;
        size_t ob = (size_t)(b * cLQ + q) * cD + h * 32;
        O[ob + l15]      = f2b(o0[r] * inv);
        O[ob + 16 + l15] = f2b(o1[r] * inv);
    }
}

// ---------------- fused residual add + LayerNorm (1 wave per 256-row) ----------------
template <int WB, int QP>
__global__ __launch_bounds__(256) void add_ln_kernel(const float* __restrict__ X,
                                                     const float* __restrict__ R,
                                                     const float* __restrict__ g,
                                                     const float* __restrict__ bt,
                                                     const float* __restrict__ qp,
                                                     float* __restrict__ out,
                                                     u16* __restrict__ outb) {
    int wave = threadIdx.x / 64;
    int lane = threadIdx.x % 64;
    int row = blockIdx.x * 4 + wave;
    const float* x = X + (size_t)row * cD;
    const float* r = R + (size_t)row * cD;
    float4 xv = *(const float4*)(x + lane * 4);
    float4 rv = *(const float4*)(r + lane * 4);
    float v0 = xv.x + rv.x, v1 = xv.y + rv.y, v2 = xv.z + rv.z, v3 = xv.w + rv.w;
    float s = v0 + v1 + v2 + v3;
    float s2 = v0 * v0 + v1 * v1 + v2 * v2 + v3 * v3;
#pragma unroll
    for (int off = 32; off > 0; off >>= 1) {
        s += __shfl_xor(s, off);
        s2 += __shfl_xor(s2, off);
    }
    float mean = s * (1.0f / 256.0f);
    float var = s2 * (1.0f / 256.0f) - mean * mean;
    float rstd = rsqrtf(var + 1e-5f);
    float4 gv = *(const float4*)(g + lane * 4);
    float4 bv = *(const float4*)(bt + lane * 4);
    float4 o;
    o.x = (v0 - mean) * rstd * gv.x + bv.x;
    o.y = (v1 - mean) * rstd * gv.y + bv.y;
    o.z = (v2 - mean) * rstd * gv.z + bv.z;
    o.w = (v3 - mean) * rstd * gv.w + bv.w;
    *(float4*)(out + (size_t)row * cD + lane * 4) = o;
    if (WB) {
        u16x4 ob = { f2b(o.x), f2b(o.y), f2b(o.z), f2b(o.w) };
        *(u16x4*)(outb + (size_t)row * cD + lane * 4) = ob;
    }
    if (QP) {
        float4 qv = *(const float4*)(qp + (size_t)row * cD + lane * 4);
        u16x4 ob = { f2b(o.x + qv.x), f2b(o.y + qv.y), f2b(o.z + qv.z), f2b(o.w + qv.w) };
        *(u16x4*)(outb + (size_t)row * cD + lane * 4) = ob;
    }
}

// ------- ms-deform-attn sampling: 8 lanes per (b,q,h) -------
// Param math de-duplicated: each lane computes {wgt[4],idx[4]} for 2 of the 16 samples,
// group exchanges via __shfl(.,8) (ds_bpermute, idle LDS pipe) instead of every lane
// redoing the ~560-op chain for all 16 samples (was VALUBusy 82%).
__global__ __launch_bounds__(256) void deform_kernel(const u16* __restrict__ value,
                                                     const float* __restrict__ oa,
                                                     const float* __restrict__ refp,
                                                     u16* __restrict__ out) {
    int t = blockIdx.x * 32 + (threadIdx.x >> 3);
    int dq = threadIdx.x & 7;
    int h = t & 7;
    int bq = t >> 3;
    int b = bq >> 10;
    const float* al = oa + (size_t)bq * 384 + 256 + h * 16;
    float wv[16];
    float mx = -1e30f;
#pragma unroll
    for (int i = 0; i < 16; ++i) { wv[i] = al[i]; mx = fmaxf(mx, wv[i]); }
    float sum = 0.f;
#pragma unroll
    for (int i = 0; i < 16; ++i) { wv[i] = __expf(wv[i] - mx); sum += wv[i]; }
    float inv = 1.f / sum;
    const float* off = oa + (size_t)bq * 384 + h * 32;
    const float* rp = refp + (size_t)bq * 8;
    // params for this lane's two samples: s = dq*2, dq*2+1
    float wgtA[4], wgtB[4];
    int   idxA[4], idxB[4];
#pragma unroll
    for (int k = 0; k < 2; ++k) {
        int s = dq * 2 + k;
        int l = s >> 2;
        int dim = 64 >> l;
        unsigned start = (16384u - (16384u >> (2 * l))) / 3u;   // 0,4096,5120,5376
        float ox = off[s * 2 + 0];
        float oy = off[s * 2 + 1];
        float x = rp[l * 2 + 0] * (float)dim + ox - 0.5f;
        float y = rp[l * 2 + 1] * (float)dim + oy - 0.5f;
        float x0f = floorf(x), y0f = floorf(y);
        float lx = x - x0f, ly = y - y0f;
        int x0 = (int)x0f, y0 = (int)y0f;
        float aw = wv[s] * inv;
        float cw[4] = {(1.f - lx) * (1.f - ly), lx * (1.f - ly),
                       (1.f - lx) * ly, lx * ly};
        int xs[4] = {x0, x0 + 1, x0, x0 + 1};
        int ys[4] = {y0, y0, y0 + 1, y0 + 1};
#pragma unroll
        for (int c = 0; c < 4; ++c) {
            int xi = xs[c], yi = ys[c];
            bool valid = (xi >= 0) && (xi < dim) && (yi >= 0) && (yi < dim);
            int xc = min(max(xi, 0), dim - 1);
            int yc = min(max(yi, 0), dim - 1);
            int ix = (int)start + yc * dim + xc;
            float wg = valid ? aw * cw[c] : 0.f;
            if (k == 0) { wgtA[c] = wg; idxA[c] = ix; }
            else        { wgtB[c] = wg; idxB[c] = ix; }
        }
    }
    const u16* vb = value + ((size_t)b * cLVTOT) * 256 + h * 32 + dq * 4;
    float a0 = 0.f, a1 = 0.f, a2 = 0.f, a3 = 0.f;
#pragma unroll
    for (int s = 0; s < 16; ++s) {
        int srcl = s >> 1;
#pragma unroll
        for (int c = 0; c < 4; ++c) {
            float wgt = __shfl((s & 1) ? wgtB[c] : wgtA[c], srcl, 8);
            int   idx = __shfl((s & 1) ? idxB[c] : idxA[c], srcl, 8);
            unsigned long long u = *(const unsigned long long*)(vb + (size_t)idx * 256);
            a0 += wgt * bl((unsigned)(u & 0xffffull));
            a1 += wgt * bl((unsigned)((u >> 16) & 0xffffull));
            a2 += wgt * bl((unsigned)((u >> 32) & 0xffffull));
            a3 += wgt * bl((unsigned)(u >> 48));
        }
    }
    u16x4 o = { f2b(a0), f2b(a1), f2b(a2), f2b(a3) };
    *(u16x4*)(out + (size_t)bq * 256 + h * 32 + dq * 4) = o;
}

extern "C" void kernel_launch(void* const* d_in, const int* in_sizes, int n_in,
                              void* d_out, int out_size, void* d_ws, size_t ws_size,
                              hipStream_t stream) {
    const float* tgt        = (const float*)d_in[0];
    const float* query_pos  = (const float*)d_in[1];
    const float* refp       = (const float*)d_in[2];
    const float* src        = (const float*)d_in[3];
    const float* in_proj_w  = (const float*)d_in[4];
    const float* in_proj_b  = (const float*)d_in[5];
    const float* out_proj_b = (const float*)d_in[7];
    const float* norm2_g    = (const float*)d_in[8];
    const float* norm2_b    = (const float*)d_in[9];
    const float* value_b    = (const float*)d_in[11];
    const float* off_b      = (const float*)d_in[13];
    const float* attw_b     = (const float*)d_in[15];
    const float* outp_b     = (const float*)d_in[17];
    const float* norm1_g    = (const float*)d_in[18];
    const float* norm1_b    = (const float*)d_in[19];
    const float* lin1_b     = (const float*)d_in[21];
    const float* lin2_b     = (const float*)d_in[23];
    const float* norm3_g    = (const float*)d_in[24];
    const float* norm3_b    = (const float*)d_in[25];

    char* W = (char*)d_ws;
    const size_t S84 = 8388608;   // 16384*256*2 B
    u16*   tgtb  = (u16*)(W + 0);
    u16*   q2b   = (u16*)(W + 0);
    u16*   qb    = (u16*)(W + 1 * S84);
    u16*   QKb   = (u16*)(W + 2 * S84);         // slots 2-3
    u16*   dtb   = (u16*)(W + 2 * S84);
    u16*   x2b   = (u16*)(W + 3 * S84);
    float* ffn2f = (float*)(W + 4 * S84);       // slots 4-5
    u16*   aob   = (u16*)(W + 5 * S84);
    float* oaf   = (float*)(W + 5 * S84);       // slots 5-7
    u16*   Vtg   = (u16*)(W + 6 * S84);
    float* t2f   = (float*)(W + 6 * S84);       // slots 6-7
    float* x1f   = (float*)(W + 8 * S84);
    float* x2f   = (float*)(W + 10 * S84);
    u16*   ffn1b = (u16*)(W + 12 * S84);
    u16*   valb  = (u16*)(W + 12 * S84 + 44564480);
    char*  wbase = W + 12 * S84 + 2 * 44564480;
    u16* wb_in   = (u16*)(wbase + 0);
    u16* wb_out  = (u16*)(wbase + 393216);
    u16* wb_val  = (u16*)(wbase + 524288);
    u16* wb_off  = (u16*)(wbase + 655360);      // off(256) + attw(128) rows contiguous
    u16* wb_outp = (u16*)(wbase + 851968);
    u16* wb_lin1 = (u16*)(wbase + 983040);
    u16* wb_lin2 = (u16*)(wbase + 1507328);
    float* biasoa= (float*)(wbase + 2031616);
    float* out = (float*)d_out;

    dim3 blk(256);

    // fused conversion pass (tgt/qb + weights + bias concat; src handled in-GEMM)
    WArgs wa;
    wa.src[0] = (const float4*)in_proj_w;  wa.src[1] = (const float4*)d_in[6];
    wa.src[2] = (const float4*)d_in[10];   wa.src[3] = (const float4*)d_in[12];
    wa.src[4] = (const float4*)d_in[14];   wa.src[5] = (const float4*)d_in[16];
    wa.src[6] = (const float4*)d_in[20];   wa.src[7] = (const float4*)d_in[22];
    prep_all<<<dim3(1273), blk, 0, stream>>>((const float4*)tgt, (const float4*)query_pos,
                                             (u16x8*)tgtb, (u16x8*)qb,
                                             wa, (u16x8*)wb_in, off_b, attw_b, biasoa);

    // QKV projection + value projection in one uniform grid (1360 val + 768 qkv blocks)
    gemm_qkv_val<<<dim3(2128), blk, 0, stream>>>(qb, tgtb, wb_in, in_proj_b, QKb, Vtg,
                                                 src, wb_val, value_b, valb);
    // MHA attention (standalone, low VGPR)
    attn_sw<<<dim3(cB * cH * 16), blk, 0, stream>>>(QKb, Vtg, aob);
    gemm64<0, 0><<<dim3(256, 2), blk, 0, stream>>>(aob, wb_out, out_proj_b, t2f, nullptr, cNTOK, 256, 256);
    add_ln_kernel<0, 1><<<dim3(4096), blk, 0, stream>>>(tgt, t2f, norm2_g, norm2_b, query_pos, x1f, q2b);

    // deformable attention (value projection already done above)
    gemm64<0, 0><<<dim3(256, 3), blk, 0, stream>>>(q2b, wb_off, biasoa, oaf, nullptr, cNTOK, 384, 256);
    deform_kernel<<<dim3(4096), blk, 0, stream>>>(valb, oaf, refp, dtb);
    gemm64<0, 0><<<dim3(256, 2), blk, 0, stream>>>(dtb, wb_outp, outp_b, t2f, nullptr, cNTOK, 256, 256);
    add_ln_kernel<1, 0><<<dim3(4096), blk, 0, stream>>>(x1f, t2f, norm1_g, norm1_b, nullptr, x2f, x2b);

    // FFN
    gemm128<1, 1><<<dim3(128, 8), blk, 0, stream>>>(x2b, wb_lin1, lin1_b, nullptr, ffn1b, cNTOK, 1024, 256);
    gemm64<0, 0><<<dim3(256, 2), blk, 0, stream>>>(ffn1b, wb_lin2, lin2_b, ffn2f, nullptr, cNTOK, 256, 1024);
    add_ln_kernel<0, 0><<<dim3(4096), blk, 0, stream>>>(x2f, ffn2f, norm3_g, norm3_b, nullptr, out, nullptr);
}